// Round 4
// baseline (414.116 us; speedup 1.0000x reference)
//
#include <hip/hip_runtime.h>
#include <hip/hip_bf16.h>
#include <cstdint>

using bf16x8 = __attribute__((ext_vector_type(8))) short;
using f32x4  = __attribute__((ext_vector_type(4))) float;
using bf16_t = __hip_bfloat16;

#define DEVI static __device__ __forceinline__

constexpr int kB = 4, kC = 256, kNH = 8, kDh = 32;
constexpr int kVP = 6, kVW = 16, kHP = 32, kHW = 3;
constexpr int kNW = 48, kP = 192, kGRID = 96;
constexpr int kRows = kB * kNW * kP;    // 36864
constexpr int kFF = 1024;
constexpr float kScale = 0.0625f;       // 1/sqrt(C)

// row -> (b, g1, g2): window (vw,hw), patch (vp,hp); rolled grid coords
DEVI void row_coords(int row, int& b, int& g1, int& g2) {
  int b_  = row / (kNW * kP);
  int rem = row - b_ * (kNW * kP);
  int w = rem / kP;
  int p = rem - w * kP;
  int vw = w / kHW, hw = w - vw * kHW;
  int vp = p >> 5,  hp = p & 31;
  int r  = vp * kVW + vw;
  int cc = hp * kHW + hw;
  g1 = r + 80;  if (g1 >= kGRID) g1 -= kGRID;
  g2 = cc + 93; if (g2 >= kGRID) g2 -= kGRID;
  b = b_;
}

DEVI float bf2f(short s) {
  union { unsigned u; float f; } c;
  c.u = ((unsigned)(unsigned short)s) << 16;
  return c.f;
}
DEVI short f2bf(float f) {
  bf16_t h = __float2bfloat16(f);
  return *reinterpret_cast<short*>(&h);
}

DEVI void gload16(const void* g, void* l) {
  __builtin_amdgcn_global_load_lds(
      (__attribute__((address_space(1))) void*)(uintptr_t)g,
      (__attribute__((address_space(3))) void*)(uintptr_t)l, 16, 0, 0);
}

// ---------------- weight convert
__global__ __launch_bounds__(256) void k_wconv(
    const float* __restrict__ wq, const float* __restrict__ wk,
    const float* __restrict__ wv, const float* __restrict__ w1,
    const float* __restrict__ w2, bf16_t* __restrict__ W) {
  const int i = blockIdx.x * 256 + threadIdx.x;
  if (i < 196608) {                       // WqkvT: n*256+k
    const int n = i >> 8, k = i & 255;
    const float* src = n < 256 ? wq : (n < 512 ? wk : wv);
    W[i] = __float2bfloat16(src[k * 256 + (n & 255)]);
  } else if (i < 458752) {                // W1T: n*256+k, n<1024
    const int j = i - 196608;
    const int n = j >> 8, k = j & 255;
    W[i] = __float2bfloat16(w1[k * 1024 + n]);
  } else if (i < 720896) {                // W2T: n*1024+k, n<256
    const int j = i - 458752;
    const int n = j >> 10, k = j & 1023;
    W[i] = __float2bfloat16(w2[k * 256 + n]);
  }
}

// ---------------- gather + LN1 -> Y bf16
__global__ __launch_bounds__(256) void k_ln1(const float* __restrict__ emb,
    const float* __restrict__ gam, const float* __restrict__ bet,
    bf16_t* __restrict__ Y) {
  const int wave = threadIdx.x >> 6, lane = threadIdx.x & 63;
  #pragma unroll
  for (int rr = 0; rr < 2; ++rr) {
    const int row = blockIdx.x * 8 + wave * 2 + rr;
    int b, g1, g2; row_coords(row, b, g1, g2);
    const float* src = emb + (((size_t)b * kGRID + g1) * kGRID + g2) * kC;
    float4 x = *reinterpret_cast<const float4*>(src + lane * 4);
    float s  = x.x + x.y + x.z + x.w;
    float sq = x.x*x.x + x.y*x.y + x.z*x.z + x.w*x.w;
    #pragma unroll
    for (int off = 32; off; off >>= 1) { s += __shfl_xor(s, off); sq += __shfl_xor(sq, off); }
    const float mean = s * (1.f / kC);
    const float rstd = rsqrtf(sq * (1.f / kC) - mean * mean + 1e-5f);
    const float4 g4 = *reinterpret_cast<const float4*>(gam + lane * 4);
    const float4 b4 = *reinterpret_cast<const float4*>(bet + lane * 4);
    short4 o;
    o.x = f2bf((x.x - mean) * rstd * g4.x + b4.x);
    o.y = f2bf((x.y - mean) * rstd * g4.y + b4.y);
    o.z = f2bf((x.z - mean) * rstd * g4.z + b4.z);
    o.w = f2bf((x.w - mean) * rstd * g4.w + b4.w);
    *reinterpret_cast<short4*>(Y + (size_t)row * kC + lane * 4) = o;
  }
}

// ---------------- re-gather + residual + LN2 -> A fp32, H bf16
__global__ __launch_bounds__(256) void k_ln2(const float* __restrict__ emb,
    const bf16_t* __restrict__ SA,
    const float* __restrict__ gam, const float* __restrict__ bet,
    float* __restrict__ A, bf16_t* __restrict__ H) {
  const int wave = threadIdx.x >> 6, lane = threadIdx.x & 63;
  #pragma unroll
  for (int rr = 0; rr < 2; ++rr) {
    const int row = blockIdx.x * 8 + wave * 2 + rr;
    int b, g1, g2; row_coords(row, b, g1, g2);
    const float* src = emb + (((size_t)b * kGRID + g1) * kGRID + g2) * kC;
    float4 x = *reinterpret_cast<const float4*>(src + lane * 4);
    short4 sv = *reinterpret_cast<const short4*>(SA + (size_t)row * kC + lane * 4);
    x.x += bf2f(sv.x); x.y += bf2f(sv.y); x.z += bf2f(sv.z); x.w += bf2f(sv.w);
    *reinterpret_cast<float4*>(A + (size_t)row * kC + lane * 4) = x;
    float s  = x.x + x.y + x.z + x.w;
    float sq = x.x*x.x + x.y*x.y + x.z*x.z + x.w*x.w;
    #pragma unroll
    for (int off = 32; off; off >>= 1) { s += __shfl_xor(s, off); sq += __shfl_xor(sq, off); }
    const float mean = s * (1.f / kC);
    const float rstd = rsqrtf(sq * (1.f / kC) - mean * mean + 1e-5f);
    const float4 g4 = *reinterpret_cast<const float4*>(gam + lane * 4);
    const float4 b4 = *reinterpret_cast<const float4*>(bet + lane * 4);
    short4 o;
    o.x = f2bf((x.x - mean) * rstd * g4.x + b4.x);
    o.y = f2bf((x.y - mean) * rstd * g4.y + b4.y);
    o.z = f2bf((x.z - mean) * rstd * g4.z + b4.z);
    o.w = f2bf((x.w - mean) * rstd * g4.w + b4.w);
    *reinterpret_cast<short4*>(H + (size_t)row * kC + lane * 4) = o;
  }
}

// ---------------- MFMA GEMM, full-K-chunk staging (K-chunk = 256)
// BM=BN=128, 4 waves (2x2), per-wave 64x64 = 4x4 16x16x32 frags.
// LDS layout [kg][128 rows][8] (kg = K/8 group): fragment ds_read_b128 hits 16
// consecutive 16B slots (2-way bank aliasing = free), staging dest is linear.
// Whole 256-wide K-panel staged in ONE shot (128 global_load_lds in flight,
// ONE vmcnt drain + barrier per chunk) -> kills the per-K-step latency stalls.
template <int KDIM, int EPI>
__global__ __launch_bounds__(256) void k_gemm(
    const bf16_t* __restrict__ Amat, const bf16_t* __restrict__ BT,
    const float* __restrict__ bias0, const float* __restrict__ bias1,
    const float* __restrict__ bias2,
    bf16_t* __restrict__ Obf, const float* __restrict__ Ares,
    float* __restrict__ Out) {
  __shared__ bf16_t As[32 * 128 * 8];    // 64 KB: [kg][row][8]
  __shared__ bf16_t Bs[32 * 128 * 8];    // 64 KB
  const int tid = threadIdx.x;
  const int wave = tid >> 6, lane = tid & 63;
  const int lr = lane & 15, kgf = lane >> 4;
  const int m0 = blockIdx.x * 128, n0 = blockIdx.y * 128;
  const int wm = (wave >> 1) * 64, wn = (wave & 1) * 64;
  f32x4 acc[4][4] = {};
  for (int kc = 0; kc < KDIM; kc += 256) {
    if (kc) __syncthreads();             // LDS reuse across chunks
    // stage full 128x256 A and B panels: 32 gloads per wave, all in flight
    #pragma unroll
    for (int i = 0; i < 16; ++i) {
      const int a = wave * 16 + i;       // 0..63 (wave-uniform)
      const int kg = a >> 1, rh = a & 1;
      gload16(Amat + (size_t)(m0 + rh * 64 + lane) * KDIM + kc + kg * 8,
              &As[(kg * 128 + rh * 64) * 8]);
      gload16(BT   + (size_t)(n0 + rh * 64 + lane) * KDIM + kc + kg * 8,
              &Bs[(kg * 128 + rh * 64) * 8]);
    }
    __syncthreads();
    #pragma unroll
    for (int kk = 0; kk < 8; ++kk) {
      const int kgg = kk * 4 + kgf;
      bf16x8 af[4], bq[4];
      #pragma unroll
      for (int m = 0; m < 4; ++m)
        af[m] = *reinterpret_cast<const bf16x8*>(&As[(kgg * 128 + wm + m * 16 + lr) * 8]);
      #pragma unroll
      for (int n = 0; n < 4; ++n)
        bq[n] = *reinterpret_cast<const bf16x8*>(&Bs[(kgg * 128 + wn + n * 16 + lr) * 8]);
      #pragma unroll
      for (int m = 0; m < 4; ++m)
        #pragma unroll
        for (int n = 0; n < 4; ++n)
          acc[m][n] = __builtin_amdgcn_mfma_f32_16x16x32_bf16(af[m], bq[n], acc[m][n], 0, 0, 0);
    }
  }
  #pragma unroll
  for (int m = 0; m < 4; ++m) {
    #pragma unroll
    for (int n = 0; n < 4; ++n) {
      #pragma unroll
      for (int r = 0; r < 4; ++r) {
        const int row = m0 + wm + m * 16 + kgf * 4 + r;
        const int col = n0 + wn + n * 16 + lr;
        float v = acc[m][n][r];
        if constexpr (EPI == 0) {
          const int which = col >> 8, c = col & 255;
          const float* bp = which == 0 ? bias0 : (which == 1 ? bias1 : bias2);
          v += bp[c];
          Obf[(size_t)which * kRows * kC + (size_t)row * kC + c] = __float2bfloat16(v);
        } else if constexpr (EPI == 1) {
          v += bias0[col];
          const float gl = 0.5f * v * (1.f + erff(v * 0.70710678118654752f));
          Obf[(size_t)row * kFF + col] = __float2bfloat16(gl);
        } else {
          v += bias0[col] + Ares[(size_t)row * kC + col];
          int b, g1, g2; row_coords(row, b, g1, g2);
          Out[(((size_t)b * kGRID + g1) * kGRID + g2) * kC + col] = v;
        }
      }
    }
  }
}

// ---------------- MFMA attention (unchanged)
constexpr int kKsPad = 40;   // rows 16B-aligned (80B), 2-way banks
constexpr int kVtPad = 200;  // rows 16B-aligned (400B), 2-way banks
constexpr int kPlPad = 200;
__global__ __launch_bounds__(256) void k_attn(
    const bf16_t* __restrict__ Q, const bf16_t* __restrict__ K,
    const bf16_t* __restrict__ V, const float* __restrict__ pos,
    bf16_t* __restrict__ SA) {
  __shared__ short Ks[kP * kKsPad];        // K rows [192][40]
  __shared__ short Vt[kDh * kVtPad];       // V^T    [32][200]
  __shared__ short Pl[4 * 16 * kPlPad];    // per-wave P m-tile [16][200]
  const int bw = blockIdx.x >> 3, h = blockIdx.x & 7;
  const int rowbase = bw * kP, colbase = h * kDh;
  const int tid = threadIdx.x, wave = tid >> 6, lane = tid & 63;
  const int lr = lane & 15, kg = lane >> 4;
  const int wq0 = wave * 48;
  const float* pb = pos + (size_t)h * kP * kP;

  #pragma unroll
  for (int i = 0; i < 3; ++i) {
    const int c = tid + i * 256;           // 768 chunks of 8 elems
    const int row = c >> 2, dch = (c & 3) * 8;
    const size_t gbase = (size_t)(rowbase + row) * kC + colbase + dch;
    bf16x8 kv = *reinterpret_cast<const bf16x8*>(K + gbase);
    *reinterpret_cast<bf16x8*>(&Ks[row * kKsPad + dch]) = kv;
    bf16x8 vv = *reinterpret_cast<const bf16x8*>(V + gbase);
    #pragma unroll
    for (int e = 0; e < 8; ++e) Vt[(dch + e) * kVtPad + row] = vv[e];
  }
  __syncthreads();

  for (int m = 0; m < 3; ++m) {
    const int rbase = wq0 + m * 16;
    bf16x8 aq = *reinterpret_cast<const bf16x8*>(
        Q + (size_t)(rowbase + rbase + lr) * kC + colbase + kg * 8);
    f32x4 s[12];
    #pragma unroll
    for (int n = 0; n < 12; ++n) {
      bf16x8 bk = *reinterpret_cast<const bf16x8*>(&Ks[(n * 16 + lr) * kKsPad + kg * 8]);
      s[n] = __builtin_amdgcn_mfma_f32_16x16x32_bf16(aq, bk, (f32x4){0.f, 0.f, 0.f, 0.f}, 0, 0, 0);
    }
    float mx[4] = {-1e30f, -1e30f, -1e30f, -1e30f};
    #pragma unroll
    for (int n = 0; n < 12; ++n) {
      #pragma unroll
      for (int r = 0; r < 4; ++r) {
        const float lg = fmaf(s[n][r], kScale,
                              pb[(size_t)(rbase + kg * 4 + r) * kP + n * 16 + lr]);
        s[n][r] = lg;
        mx[r] = fmaxf(mx[r], lg);
      }
    }
    #pragma unroll
    for (int r = 0; r < 4; ++r)
      #pragma unroll
      for (int off = 8; off; off >>= 1) mx[r] = fmaxf(mx[r], __shfl_xor(mx[r], off));
    float sm[4] = {0.f, 0.f, 0.f, 0.f};
    #pragma unroll
    for (int n = 0; n < 12; ++n)
      #pragma unroll
      for (int r = 0; r < 4; ++r) {
        const float e = __expf(s[n][r] - mx[r]);
        s[n][r] = e;
        sm[r] += e;
      }
    #pragma unroll
    for (int r = 0; r < 4; ++r) {
      #pragma unroll
      for (int off = 8; off; off >>= 1) sm[r] += __shfl_xor(sm[r], off);
      sm[r] = 1.f / sm[r];
    }
    #pragma unroll
    for (int n = 0; n < 12; ++n)
      #pragma unroll
      for (int r = 0; r < 4; ++r)
        Pl[(wave * 16 + kg * 4 + r) * kPlPad + n * 16 + lr] = f2bf(s[n][r] * sm[r]);
    f32x4 o0 = {0.f, 0.f, 0.f, 0.f}, o1 = {0.f, 0.f, 0.f, 0.f};
    #pragma unroll
    for (int kk = 0; kk < 6; ++kk) {
      bf16x8 ap = *reinterpret_cast<const bf16x8*>(&Pl[(wave * 16 + lr) * kPlPad + kk * 32 + kg * 8]);
      bf16x8 b0 = *reinterpret_cast<const bf16x8*>(&Vt[lr * kVtPad + kk * 32 + kg * 8]);
      bf16x8 b1 = *reinterpret_cast<const bf16x8*>(&Vt[(16 + lr) * kVtPad + kk * 32 + kg * 8]);
      o0 = __builtin_amdgcn_mfma_f32_16x16x32_bf16(ap, b0, o0, 0, 0, 0);
      o1 = __builtin_amdgcn_mfma_f32_16x16x32_bf16(ap, b1, o1, 0, 0, 0);
    }
    bf16_t* sp = SA + (size_t)(rowbase + rbase + kg * 4) * kC + colbase;
    #pragma unroll
    for (int r = 0; r < 4; ++r) {
      sp[(size_t)r * kC + lr]      = __float2bfloat16(o0[r]);
      sp[(size_t)r * kC + 16 + lr] = __float2bfloat16(o1[r]);
    }
  }
}

extern "C" void kernel_launch(void* const* d_in, const int* in_sizes, int n_in,
                              void* d_out, int out_size, void* d_ws, size_t ws_size,
                              hipStream_t stream) {
  const float* emb  = (const float*)d_in[0];
  const float* ln1g = (const float*)d_in[1];
  const float* ln1b = (const float*)d_in[2];
  const float* wq   = (const float*)d_in[3];
  const float* bq   = (const float*)d_in[4];
  const float* wk   = (const float*)d_in[5];
  const float* bk   = (const float*)d_in[6];
  const float* wv   = (const float*)d_in[7];
  const float* bv   = (const float*)d_in[8];
  const float* pos  = (const float*)d_in[9];
  const float* ln2g = (const float*)d_in[10];
  const float* ln2b = (const float*)d_in[11];
  const float* w1   = (const float*)d_in[12];
  const float* b1   = (const float*)d_in[13];
  const float* w2   = (const float*)d_in[14];
  const float* b2   = (const float*)d_in[15];

  char* ws = (char*)d_ws;
  const size_t nYb = (size_t)kRows * kC * 2;               // 18,874,368 B
  bf16_t* Y    = (bf16_t*)(ws);                            // [0, 18.9M)
  bf16_t* Qb   = (bf16_t*)(ws + nYb);                      // Q,K,V consecutive
  bf16_t* SAb  = (bf16_t*)(ws + nYb * 4);                  // [75.5M, 94.4M)
  float*  Abuf = (float*) (ws + nYb * 5);                  // [94.4M, 132.1M)
  bf16_t* H    = (bf16_t*)(ws + nYb * 5 + (size_t)kRows * kC * 4);  // [132.1M, 151M)
  bf16_t* G    = (bf16_t*)(ws);                            // alias dead Y/Q/K/V
  bf16_t* W    = (bf16_t*)(ws + nYb * 5 + (size_t)kRows * kC * 4 + nYb);
  bf16_t* WqkvT = W;
  bf16_t* W1T   = W + 768 * 256;
  bf16_t* W2T   = W1T + 1024 * 256;

  k_wconv<<<2816, 256, 0, stream>>>(wq, wk, wv, w1, w2, W);
  k_ln1<<<kRows / 8, 256, 0, stream>>>(emb, ln1g, ln1b, Y);
  k_gemm<256, 0><<<dim3(kRows / 128, 6), 256, 0, stream>>>(
      Y, WqkvT, bq, bk, bv, Qb, nullptr, nullptr);
  k_attn<<<kB * kNW * kNH, 256, 0, stream>>>(
      Qb, Qb + (size_t)kRows * kC, Qb + 2 * (size_t)kRows * kC, pos, SAb);
  k_ln2<<<kRows / 8, 256, 0, stream>>>(emb, SAb, ln2g, ln2b, Abuf, H);
  k_gemm<256, 1><<<dim3(kRows / 128, 8), 256, 0, stream>>>(
      H, W1T, b1, nullptr, nullptr, G, nullptr, nullptr);
  k_gemm<1024, 2><<<dim3(kRows / 128, 2), 256, 0, stream>>>(
      G, W2T, b2, nullptr, nullptr, nullptr, Abuf, (float*)d_out);
}

// Round 5
// 285.877 us; speedup vs baseline: 1.4486x; 1.4486x over previous
//
#include <hip/hip_runtime.h>
#include <hip/hip_bf16.h>
#include <cstdint>

using bf16x8 = __attribute__((ext_vector_type(8))) short;
using f32x4  = __attribute__((ext_vector_type(4))) float;
using bf16_t = __hip_bfloat16;

#define DEVI static __device__ __forceinline__

constexpr int kB = 4, kC = 256, kNH = 8, kDh = 32;
constexpr int kVP = 6, kVW = 16, kHP = 32, kHW = 3;
constexpr int kNW = 48, kP = 192, kGRID = 96;
constexpr int kRows = kB * kNW * kP;    // 36864
constexpr int kFF = 1024;
constexpr float kScale = 0.0625f;       // 1/sqrt(C)

// row -> (b, g1, g2): window (vw,hw), patch (vp,hp); rolled grid coords
DEVI void row_coords(int row, int& b, int& g1, int& g2) {
  int b_  = row / (kNW * kP);
  int rem = row - b_ * (kNW * kP);
  int w = rem / kP;
  int p = rem - w * kP;
  int vw = w / kHW, hw = w - vw * kHW;
  int vp = p >> 5,  hp = p & 31;
  int r  = vp * kVW + vw;
  int cc = hp * kHW + hw;
  g1 = r + 80;  if (g1 >= kGRID) g1 -= kGRID;
  g2 = cc + 93; if (g2 >= kGRID) g2 -= kGRID;
  b = b_;
}

DEVI float bf2f(short s) {
  union { unsigned u; float f; } c;
  c.u = ((unsigned)(unsigned short)s) << 16;
  return c.f;
}
DEVI short f2bf(float f) {
  bf16_t h = __float2bfloat16(f);
  return *reinterpret_cast<short*>(&h);
}

DEVI void gload16(const void* g, void* l) {
  __builtin_amdgcn_global_load_lds(
      (__attribute__((address_space(1))) void*)(uintptr_t)g,
      (__attribute__((address_space(3))) void*)(uintptr_t)l, 16, 0, 0);
}

// ---------------- weight convert
__global__ __launch_bounds__(256) void k_wconv(
    const float* __restrict__ wq, const float* __restrict__ wk,
    const float* __restrict__ wv, const float* __restrict__ w1,
    const float* __restrict__ w2, bf16_t* __restrict__ W) {
  const int i = blockIdx.x * 256 + threadIdx.x;
  if (i < 196608) {                       // WqkvT: n*256+k
    const int n = i >> 8, k = i & 255;
    const float* src = n < 256 ? wq : (n < 512 ? wk : wv);
    W[i] = __float2bfloat16(src[k * 256 + (n & 255)]);
  } else if (i < 458752) {                // W1T: n*256+k, n<1024
    const int j = i - 196608;
    const int n = j >> 8, k = j & 255;
    W[i] = __float2bfloat16(w1[k * 1024 + n]);
  } else if (i < 720896) {                // W2T: n*1024+k, n<256
    const int j = i - 458752;
    const int n = j >> 10, k = j & 1023;
    W[i] = __float2bfloat16(w2[k * 256 + n]);
  }
}

// ---------------- gather + LN1 -> Y bf16
__global__ __launch_bounds__(256) void k_ln1(const float* __restrict__ emb,
    const float* __restrict__ gam, const float* __restrict__ bet,
    bf16_t* __restrict__ Y) {
  const int wave = threadIdx.x >> 6, lane = threadIdx.x & 63;
  #pragma unroll
  for (int rr = 0; rr < 2; ++rr) {
    const int row = blockIdx.x * 8 + wave * 2 + rr;
    int b, g1, g2; row_coords(row, b, g1, g2);
    const float* src = emb + (((size_t)b * kGRID + g1) * kGRID + g2) * kC;
    float4 x = *reinterpret_cast<const float4*>(src + lane * 4);
    float s  = x.x + x.y + x.z + x.w;
    float sq = x.x*x.x + x.y*x.y + x.z*x.z + x.w*x.w;
    #pragma unroll
    for (int off = 32; off; off >>= 1) { s += __shfl_xor(s, off); sq += __shfl_xor(sq, off); }
    const float mean = s * (1.f / kC);
    const float rstd = rsqrtf(sq * (1.f / kC) - mean * mean + 1e-5f);
    const float4 g4 = *reinterpret_cast<const float4*>(gam + lane * 4);
    const float4 b4 = *reinterpret_cast<const float4*>(bet + lane * 4);
    short4 o;
    o.x = f2bf((x.x - mean) * rstd * g4.x + b4.x);
    o.y = f2bf((x.y - mean) * rstd * g4.y + b4.y);
    o.z = f2bf((x.z - mean) * rstd * g4.z + b4.z);
    o.w = f2bf((x.w - mean) * rstd * g4.w + b4.w);
    *reinterpret_cast<short4*>(Y + (size_t)row * kC + lane * 4) = o;
  }
}

// ---------------- re-gather + residual + LN2 -> A fp32, H bf16
__global__ __launch_bounds__(256) void k_ln2(const float* __restrict__ emb,
    const bf16_t* __restrict__ SA,
    const float* __restrict__ gam, const float* __restrict__ bet,
    float* __restrict__ A, bf16_t* __restrict__ H) {
  const int wave = threadIdx.x >> 6, lane = threadIdx.x & 63;
  #pragma unroll
  for (int rr = 0; rr < 2; ++rr) {
    const int row = blockIdx.x * 8 + wave * 2 + rr;
    int b, g1, g2; row_coords(row, b, g1, g2);
    const float* src = emb + (((size_t)b * kGRID + g1) * kGRID + g2) * kC;
    float4 x = *reinterpret_cast<const float4*>(src + lane * 4);
    short4 sv = *reinterpret_cast<const short4*>(SA + (size_t)row * kC + lane * 4);
    x.x += bf2f(sv.x); x.y += bf2f(sv.y); x.z += bf2f(sv.z); x.w += bf2f(sv.w);
    *reinterpret_cast<float4*>(A + (size_t)row * kC + lane * 4) = x;
    float s  = x.x + x.y + x.z + x.w;
    float sq = x.x*x.x + x.y*x.y + x.z*x.z + x.w*x.w;
    #pragma unroll
    for (int off = 32; off; off >>= 1) { s += __shfl_xor(s, off); sq += __shfl_xor(sq, off); }
    const float mean = s * (1.f / kC);
    const float rstd = rsqrtf(sq * (1.f / kC) - mean * mean + 1e-5f);
    const float4 g4 = *reinterpret_cast<const float4*>(gam + lane * 4);
    const float4 b4 = *reinterpret_cast<const float4*>(bet + lane * 4);
    short4 o;
    o.x = f2bf((x.x - mean) * rstd * g4.x + b4.x);
    o.y = f2bf((x.y - mean) * rstd * g4.y + b4.y);
    o.z = f2bf((x.z - mean) * rstd * g4.z + b4.z);
    o.w = f2bf((x.w - mean) * rstd * g4.w + b4.w);
    *reinterpret_cast<short4*>(H + (size_t)row * kC + lane * 4) = o;
  }
}

// ---------------- MFMA GEMM: BM=256 x BN tile, BK=64, 8 waves (2m x 4n),
// per-wave 128 x BN/4. Double-buffered LDS (2-phase T3-minimum: stage t+1
// BEFORE compute t, one barrier per K-step). LDS layout [kg][rows][8]
// (proven conflict-free + gload-linear in R4). Grid 1D, n-fast + XCD-chunked
// swizzle so same-A-panel blocks land consecutively on one XCD (T1).
template <int KDIM, int EPI, int BN, int GX>
__global__ __launch_bounds__(512, 2) void k_gemm2(
    const bf16_t* __restrict__ Amat, const bf16_t* __restrict__ BT,
    const float* __restrict__ bias0, const float* __restrict__ bias1,
    const float* __restrict__ bias2,
    bf16_t* __restrict__ Obf, const float* __restrict__ Ares,
    float* __restrict__ Out) {
  constexpr int FN = BN / 64;            // frags per wave in n (4 or 2)
  __shared__ bf16_t As[2][8 * 256 * 8];  // 32 KB per buffer
  __shared__ bf16_t Bs[2][8 * BN * 8];
  const int tid = threadIdx.x;
  const int wave = tid >> 6, lane = tid & 63;
  const int lr = lane & 15, kgf = lane >> 4;
  const int nwg = GX * (kRows / 256);
  const int wg = (blockIdx.x & 7) * (nwg >> 3) + (blockIdx.x >> 3);
  const int m0 = (wg / GX) * 256, n0 = (wg % GX) * BN;
  const int wm = (wave >> 2) * 128, wn = (wave & 3) * (BN / 4);

  auto stage = [&](int sbuf, int k0) {
    #pragma unroll
    for (int i = 0; i < 4; ++i)
      gload16(Amat + (size_t)(m0 + i * 64 + lane) * KDIM + k0 + wave * 8,
              &As[sbuf][(wave * 256 + i * 64) * 8]);
    #pragma unroll
    for (int i = 0; i < FN; ++i)
      gload16(BT + (size_t)(n0 + i * 64 + lane) * KDIM + k0 + wave * 8,
              &Bs[sbuf][(wave * BN + i * 64) * 8]);
  };

  f32x4 acc[8][FN] = {};
  stage(0, 0);
  __syncthreads();
  int buf = 0;
  constexpr int NT = KDIM / 64;
  for (int t = 0; t < NT; ++t) {
    if (t + 1 < NT) stage(buf ^ 1, (t + 1) * 64);
    #pragma unroll
    for (int kk = 0; kk < 2; ++kk) {
      const int kgg = kk * 4 + kgf;
      bf16x8 af[8], bq[FN];
      #pragma unroll
      for (int m = 0; m < 8; ++m)
        af[m] = *reinterpret_cast<const bf16x8*>(&As[buf][(kgg * 256 + wm + m * 16 + lr) * 8]);
      #pragma unroll
      for (int n = 0; n < FN; ++n)
        bq[n] = *reinterpret_cast<const bf16x8*>(&Bs[buf][(kgg * BN + wn + n * 16 + lr) * 8]);
      #pragma unroll
      for (int m = 0; m < 8; ++m)
        #pragma unroll
        for (int n = 0; n < FN; ++n)
          acc[m][n] = __builtin_amdgcn_mfma_f32_16x16x32_bf16(af[m], bq[n], acc[m][n], 0, 0, 0);
    }
    __syncthreads();
    buf ^= 1;
  }
  #pragma unroll
  for (int m = 0; m < 8; ++m) {
    #pragma unroll
    for (int n = 0; n < FN; ++n) {
      #pragma unroll
      for (int r = 0; r < 4; ++r) {
        const int row = m0 + wm + m * 16 + kgf * 4 + r;
        const int col = n0 + wn + n * 16 + lr;
        float v = acc[m][n][r];
        if constexpr (EPI == 0) {
          const int which = col >> 8, c = col & 255;
          const float* bp = which == 0 ? bias0 : (which == 1 ? bias1 : bias2);
          v += bp[c];
          Obf[(size_t)which * kRows * kC + (size_t)row * kC + c] = __float2bfloat16(v);
        } else if constexpr (EPI == 1) {
          v += bias0[col];
          const float gl = 0.5f * v * (1.f + erff(v * 0.70710678118654752f));
          Obf[(size_t)row * kFF + col] = __float2bfloat16(gl);
        } else {
          v += bias0[col] + Ares[(size_t)row * kC + col];
          int b, g1, g2; row_coords(row, b, g1, g2);
          Out[(((size_t)b * kGRID + g1) * kGRID + g2) * kC + col] = v;
        }
      }
    }
  }
}

// ---------------- MFMA attention (unchanged)
constexpr int kKsPad = 40;   // rows 16B-aligned (80B), 2-way banks
constexpr int kVtPad = 200;  // rows 16B-aligned (400B), 2-way banks
constexpr int kPlPad = 200;
__global__ __launch_bounds__(256) void k_attn(
    const bf16_t* __restrict__ Q, const bf16_t* __restrict__ K,
    const bf16_t* __restrict__ V, const float* __restrict__ pos,
    bf16_t* __restrict__ SA) {
  __shared__ short Ks[kP * kKsPad];        // K rows [192][40]
  __shared__ short Vt[kDh * kVtPad];       // V^T    [32][200]
  __shared__ short Pl[4 * 16 * kPlPad];    // per-wave P m-tile [16][200]
  const int bw = blockIdx.x >> 3, h = blockIdx.x & 7;
  const int rowbase = bw * kP, colbase = h * kDh;
  const int tid = threadIdx.x, wave = tid >> 6, lane = tid & 63;
  const int lr = lane & 15, kg = lane >> 4;
  const int wq0 = wave * 48;
  const float* pb = pos + (size_t)h * kP * kP;

  #pragma unroll
  for (int i = 0; i < 3; ++i) {
    const int c = tid + i * 256;           // 768 chunks of 8 elems
    const int row = c >> 2, dch = (c & 3) * 8;
    const size_t gbase = (size_t)(rowbase + row) * kC + colbase + dch;
    bf16x8 kv = *reinterpret_cast<const bf16x8*>(K + gbase);
    *reinterpret_cast<bf16x8*>(&Ks[row * kKsPad + dch]) = kv;
    bf16x8 vv = *reinterpret_cast<const bf16x8*>(V + gbase);
    #pragma unroll
    for (int e = 0; e < 8; ++e) Vt[(dch + e) * kVtPad + row] = vv[e];
  }
  __syncthreads();

  for (int m = 0; m < 3; ++m) {
    const int rbase = wq0 + m * 16;
    bf16x8 aq = *reinterpret_cast<const bf16x8*>(
        Q + (size_t)(rowbase + rbase + lr) * kC + colbase + kg * 8);
    f32x4 s[12];
    #pragma unroll
    for (int n = 0; n < 12; ++n) {
      bf16x8 bk = *reinterpret_cast<const bf16x8*>(&Ks[(n * 16 + lr) * kKsPad + kg * 8]);
      s[n] = __builtin_amdgcn_mfma_f32_16x16x32_bf16(aq, bk, (f32x4){0.f, 0.f, 0.f, 0.f}, 0, 0, 0);
    }
    float mx[4] = {-1e30f, -1e30f, -1e30f, -1e30f};
    #pragma unroll
    for (int n = 0; n < 12; ++n) {
      #pragma unroll
      for (int r = 0; r < 4; ++r) {
        const float lg = fmaf(s[n][r], kScale,
                              pb[(size_t)(rbase + kg * 4 + r) * kP + n * 16 + lr]);
        s[n][r] = lg;
        mx[r] = fmaxf(mx[r], lg);
      }
    }
    #pragma unroll
    for (int r = 0; r < 4; ++r)
      #pragma unroll
      for (int off = 8; off; off >>= 1) mx[r] = fmaxf(mx[r], __shfl_xor(mx[r], off));
    float sm[4] = {0.f, 0.f, 0.f, 0.f};
    #pragma unroll
    for (int n = 0; n < 12; ++n)
      #pragma unroll
      for (int r = 0; r < 4; ++r) {
        const float e = __expf(s[n][r] - mx[r]);
        s[n][r] = e;
        sm[r] += e;
      }
    #pragma unroll
    for (int r = 0; r < 4; ++r) {
      #pragma unroll
      for (int off = 8; off; off >>= 1) sm[r] += __shfl_xor(sm[r], off);
      sm[r] = 1.f / sm[r];
    }
    #pragma unroll
    for (int n = 0; n < 12; ++n)
      #pragma unroll
      for (int r = 0; r < 4; ++r)
        Pl[(wave * 16 + kg * 4 + r) * kPlPad + n * 16 + lr] = f2bf(s[n][r] * sm[r]);
    f32x4 o0 = {0.f, 0.f, 0.f, 0.f}, o1 = {0.f, 0.f, 0.f, 0.f};
    #pragma unroll
    for (int kk = 0; kk < 6; ++kk) {
      bf16x8 ap = *reinterpret_cast<const bf16x8*>(&Pl[(wave * 16 + lr) * kPlPad + kk * 32 + kg * 8]);
      bf16x8 b0 = *reinterpret_cast<const bf16x8*>(&Vt[lr * kVtPad + kk * 32 + kg * 8]);
      bf16x8 b1 = *reinterpret_cast<const bf16x8*>(&Vt[(16 + lr) * kVtPad + kk * 32 + kg * 8]);
      o0 = __builtin_amdgcn_mfma_f32_16x16x32_bf16(ap, b0, o0, 0, 0, 0);
      o1 = __builtin_amdgcn_mfma_f32_16x16x32_bf16(ap, b1, o1, 0, 0, 0);
    }
    bf16_t* sp = SA + (size_t)(rowbase + rbase + kg * 4) * kC + colbase;
    #pragma unroll
    for (int r = 0; r < 4; ++r) {
      sp[(size_t)r * kC + lr]      = __float2bfloat16(o0[r]);
      sp[(size_t)r * kC + 16 + lr] = __float2bfloat16(o1[r]);
    }
  }
}

extern "C" void kernel_launch(void* const* d_in, const int* in_sizes, int n_in,
                              void* d_out, int out_size, void* d_ws, size_t ws_size,
                              hipStream_t stream) {
  const float* emb  = (const float*)d_in[0];
  const float* ln1g = (const float*)d_in[1];
  const float* ln1b = (const float*)d_in[2];
  const float* wq   = (const float*)d_in[3];
  const float* bq   = (const float*)d_in[4];
  const float* wk   = (const float*)d_in[5];
  const float* bk   = (const float*)d_in[6];
  const float* wv   = (const float*)d_in[7];
  const float* bv   = (const float*)d_in[8];
  const float* pos  = (const float*)d_in[9];
  const float* ln2g = (const float*)d_in[10];
  const float* ln2b = (const float*)d_in[11];
  const float* w1   = (const float*)d_in[12];
  const float* b1   = (const float*)d_in[13];
  const float* w2   = (const float*)d_in[14];
  const float* b2   = (const float*)d_in[15];

  char* ws = (char*)d_ws;
  const size_t nYb = (size_t)kRows * kC * 2;               // 18,874,368 B
  bf16_t* Y    = (bf16_t*)(ws);                            // [0, 18.9M)
  bf16_t* Qb   = (bf16_t*)(ws + nYb);                      // Q,K,V consecutive
  bf16_t* SAb  = (bf16_t*)(ws + nYb * 4);                  // [75.5M, 94.4M)
  float*  Abuf = (float*) (ws + nYb * 5);                  // [94.4M, 132.1M)
  bf16_t* H    = (bf16_t*)(ws + nYb * 5 + (size_t)kRows * kC * 4);  // [132.1M, 151M)
  bf16_t* G    = (bf16_t*)(ws);                            // alias dead Y/Q/K/V
  bf16_t* W    = (bf16_t*)(ws + nYb * 5 + (size_t)kRows * kC * 4 + nYb);
  bf16_t* WqkvT = W;
  bf16_t* W1T   = W + 768 * 256;
  bf16_t* W2T   = W1T + 1024 * 256;

  k_wconv<<<2816, 256, 0, stream>>>(wq, wk, wv, w1, w2, W);
  k_ln1<<<kRows / 8, 256, 0, stream>>>(emb, ln1g, ln1b, Y);
  k_gemm2<256, 0, 256, 3><<<3 * (kRows / 256), 512, 0, stream>>>(
      Y, WqkvT, bq, bk, bv, Qb, nullptr, nullptr);
  k_attn<<<kB * kNW * kNH, 256, 0, stream>>>(
      Qb, Qb + (size_t)kRows * kC, Qb + 2 * (size_t)kRows * kC, pos, SAb);
  k_ln2<<<kRows / 8, 256, 0, stream>>>(emb, SAb, ln2g, ln2b, Abuf, H);
  k_gemm2<256, 1, 256, 4><<<4 * (kRows / 256), 512, 0, stream>>>(
      H, W1T, b1, nullptr, nullptr, G, nullptr, nullptr);
  k_gemm2<1024, 2, 128, 2><<<2 * (kRows / 256), 512, 0, stream>>>(
      G, W2T, b2, nullptr, nullptr, nullptr, Abuf, (float*)d_out);
}

// Round 6
// 199.793 us; speedup vs baseline: 2.0727x; 1.4309x over previous
//
#include <hip/hip_runtime.h>
#include <hip/hip_bf16.h>
#include <cstdint>

using bf16x8 = __attribute__((ext_vector_type(8))) short;
using f32x4  = __attribute__((ext_vector_type(4))) float;
using bf16_t = __hip_bfloat16;

#define DEVI static __device__ __forceinline__

constexpr int kB = 4, kC = 256, kNH = 8, kDh = 32;
constexpr int kVP = 6, kVW = 16, kHP = 32, kHW = 3;
constexpr int kNW = 48, kP = 192, kGRID = 96;
constexpr int kRows = kB * kNW * kP;    // 36864
constexpr int kFF = 1024;
constexpr float kScale = 0.0625f;       // 1/sqrt(C)

// row -> (b, g1, g2): window (vw,hw), patch (vp,hp); rolled grid coords
DEVI void row_coords(int row, int& b, int& g1, int& g2) {
  int b_  = row / (kNW * kP);
  int rem = row - b_ * (kNW * kP);
  int w = rem / kP;
  int p = rem - w * kP;
  int vw = w / kHW, hw = w - vw * kHW;
  int vp = p >> 5,  hp = p & 31;
  int r  = vp * kVW + vw;
  int cc = hp * kHW + hw;
  g1 = r + 80;  if (g1 >= kGRID) g1 -= kGRID;
  g2 = cc + 93; if (g2 >= kGRID) g2 -= kGRID;
  b = b_;
}

DEVI float bf2f(short s) {
  union { unsigned u; float f; } c;
  c.u = ((unsigned)(unsigned short)s) << 16;
  return c.f;
}
DEVI short f2bf(float f) {
  bf16_t h = __float2bfloat16(f);
  return *reinterpret_cast<short*>(&h);
}

DEVI void gload16(const void* g, void* l) {
  __builtin_amdgcn_global_load_lds(
      (__attribute__((address_space(1))) void*)(uintptr_t)g,
      (__attribute__((address_space(3))) void*)(uintptr_t)l, 16, 0, 0);
}

// ---------------- weight convert
__global__ __launch_bounds__(256) void k_wconv(
    const float* __restrict__ wq, const float* __restrict__ wk,
    const float* __restrict__ wv, const float* __restrict__ w1,
    const float* __restrict__ w2, bf16_t* __restrict__ W) {
  const int i = blockIdx.x * 256 + threadIdx.x;
  if (i < 196608) {                       // WqkvT: n*256+k
    const int n = i >> 8, k = i & 255;
    const float* src = n < 256 ? wq : (n < 512 ? wk : wv);
    W[i] = __float2bfloat16(src[k * 256 + (n & 255)]);
  } else if (i < 458752) {                // W1T: n*256+k, n<1024
    const int j = i - 196608;
    const int n = j >> 8, k = j & 255;
    W[i] = __float2bfloat16(w1[k * 1024 + n]);
  } else if (i < 720896) {                // W2T: n*1024+k, n<256
    const int j = i - 458752;
    const int n = j >> 10, k = j & 1023;
    W[i] = __float2bfloat16(w2[k * 256 + n]);
  }
}

// ---------------- gather + LN1 -> Y bf16
__global__ __launch_bounds__(256) void k_ln1(const float* __restrict__ emb,
    const float* __restrict__ gam, const float* __restrict__ bet,
    bf16_t* __restrict__ Y) {
  const int wave = threadIdx.x >> 6, lane = threadIdx.x & 63;
  #pragma unroll
  for (int rr = 0; rr < 2; ++rr) {
    const int row = blockIdx.x * 8 + wave * 2 + rr;
    int b, g1, g2; row_coords(row, b, g1, g2);
    const float* src = emb + (((size_t)b * kGRID + g1) * kGRID + g2) * kC;
    float4 x = *reinterpret_cast<const float4*>(src + lane * 4);
    float s  = x.x + x.y + x.z + x.w;
    float sq = x.x*x.x + x.y*x.y + x.z*x.z + x.w*x.w;
    #pragma unroll
    for (int off = 32; off; off >>= 1) { s += __shfl_xor(s, off); sq += __shfl_xor(sq, off); }
    const float mean = s * (1.f / kC);
    const float rstd = rsqrtf(sq * (1.f / kC) - mean * mean + 1e-5f);
    const float4 g4 = *reinterpret_cast<const float4*>(gam + lane * 4);
    const float4 b4 = *reinterpret_cast<const float4*>(bet + lane * 4);
    short4 o;
    o.x = f2bf((x.x - mean) * rstd * g4.x + b4.x);
    o.y = f2bf((x.y - mean) * rstd * g4.y + b4.y);
    o.z = f2bf((x.z - mean) * rstd * g4.z + b4.z);
    o.w = f2bf((x.w - mean) * rstd * g4.w + b4.w);
    *reinterpret_cast<short4*>(Y + (size_t)row * kC + lane * 4) = o;
  }
}

// ---------------- re-gather + residual + LN2 -> A fp32, H bf16
__global__ __launch_bounds__(256) void k_ln2(const float* __restrict__ emb,
    const bf16_t* __restrict__ SA,
    const float* __restrict__ gam, const float* __restrict__ bet,
    float* __restrict__ A, bf16_t* __restrict__ H) {
  const int wave = threadIdx.x >> 6, lane = threadIdx.x & 63;
  #pragma unroll
  for (int rr = 0; rr < 2; ++rr) {
    const int row = blockIdx.x * 8 + wave * 2 + rr;
    int b, g1, g2; row_coords(row, b, g1, g2);
    const float* src = emb + (((size_t)b * kGRID + g1) * kGRID + g2) * kC;
    float4 x = *reinterpret_cast<const float4*>(src + lane * 4);
    short4 sv = *reinterpret_cast<const short4*>(SA + (size_t)row * kC + lane * 4);
    x.x += bf2f(sv.x); x.y += bf2f(sv.y); x.z += bf2f(sv.z); x.w += bf2f(sv.w);
    *reinterpret_cast<float4*>(A + (size_t)row * kC + lane * 4) = x;
    float s  = x.x + x.y + x.z + x.w;
    float sq = x.x*x.x + x.y*x.y + x.z*x.z + x.w*x.w;
    #pragma unroll
    for (int off = 32; off; off >>= 1) { s += __shfl_xor(s, off); sq += __shfl_xor(sq, off); }
    const float mean = s * (1.f / kC);
    const float rstd = rsqrtf(sq * (1.f / kC) - mean * mean + 1e-5f);
    const float4 g4 = *reinterpret_cast<const float4*>(gam + lane * 4);
    const float4 b4 = *reinterpret_cast<const float4*>(bet + lane * 4);
    short4 o;
    o.x = f2bf((x.x - mean) * rstd * g4.x + b4.x);
    o.y = f2bf((x.y - mean) * rstd * g4.y + b4.y);
    o.z = f2bf((x.z - mean) * rstd * g4.z + b4.z);
    o.w = f2bf((x.w - mean) * rstd * g4.w + b4.w);
    *reinterpret_cast<short4*>(H + (size_t)row * kC + lane * 4) = o;
  }
}

// ---------------- MFMA GEMM: 128x128 tile, BK=64, 4 waves (2x2), wave 64x64.
// LDS half-tile row-major [128][64] (128B rows). Staging: 8 lanes/row cover a
// full 128B line (coalesced); T2 XOR swizzle (16B slot s^=(row&7)) applied on
// BOTH the pre-swizzled global source (permute within the line) and the
// ds_read address (rule #21) -> conflict-free reads. Double-buffered, K-loop
// fully unrolled so buffer indices are static (compiler can disambiguate
// As[0]/As[1] and keep prefetch loads in flight across the ds_reads).
// Grid: 1D, n-fast + XCD-chunked swizzle (T1, proven FETCH win in R5).
template <int KDIM, int EPI, int GX>
__global__ __launch_bounds__(256, 2) void k_gemm3(
    const bf16_t* __restrict__ Amat, const bf16_t* __restrict__ BT,
    const float* __restrict__ bias0, const float* __restrict__ bias1,
    const float* __restrict__ bias2,
    bf16_t* __restrict__ Obf, const float* __restrict__ Ares,
    float* __restrict__ Out) {
  __shared__ bf16_t As[2][128 * 64];     // 16 KB per buffer
  __shared__ bf16_t Bs[2][128 * 64];
  const int tid = threadIdx.x;
  const int wave = tid >> 6, lane = tid & 63;
  const int lr = lane & 15, kgf = lane >> 4;
  const int nwg = (kRows / 128) * GX;
  const int wg = (blockIdx.x & 7) * (nwg >> 3) + (blockIdx.x >> 3);
  const int m0 = (wg / GX) * 128, n0 = (wg % GX) * 128;
  const int wm = (wave >> 1) * 64, wn = (wave & 1) * 64;
  // staging geometry: chunk = 8 rows x 64 cols (1 KB); lane -> row c*8+(l>>3),
  // 16B slot (l&7); global slot pre-swizzled: (l&7)^(l>>3) = (l&7)^(row&7)
  const int srow = lane >> 3;
  const int scol = ((lane & 7) ^ srow) << 3;           // element offset in row

  auto stage = [&](bf16_t* aDst, bf16_t* bDst, int k0) {
    #pragma unroll
    for (int i = 0; i < 4; ++i) {
      const int c = wave * 4 + i;                      // chunk 0..15
      const int row = c * 8 + srow;
      gload16(Amat + (size_t)(m0 + row) * KDIM + k0 + scol, aDst + c * 512);
      gload16(BT   + (size_t)(n0 + row) * KDIM + k0 + scol, bDst + c * 512);
    }
  };

  f32x4 acc[4][4] = {};
  auto compute = [&](const bf16_t* aSrc, const bf16_t* bSrc) {
    #pragma unroll
    for (int kk = 0; kk < 2; ++kk) {
      const int kgg = kk * 4 + kgf;                    // 16B k-slot 0..7
      bf16x8 af[4], bq[4];
      #pragma unroll
      for (int m = 0; m < 4; ++m) {
        const int r = wm + m * 16 + lr;
        af[m] = *reinterpret_cast<const bf16x8*>(aSrc + r * 64 + ((kgg ^ (r & 7)) << 3));
      }
      #pragma unroll
      for (int n = 0; n < 4; ++n) {
        const int r = wn + n * 16 + lr;
        bq[n] = *reinterpret_cast<const bf16x8*>(bSrc + r * 64 + ((kgg ^ (r & 7)) << 3));
      }
      #pragma unroll
      for (int m = 0; m < 4; ++m)
        #pragma unroll
        for (int n = 0; n < 4; ++n)
          acc[m][n] = __builtin_amdgcn_mfma_f32_16x16x32_bf16(af[m], bq[n], acc[m][n], 0, 0, 0);
    }
  };

  stage(As[0], Bs[0], 0);
  __syncthreads();
  constexpr int NT = KDIM / 64;
  #pragma unroll
  for (int t = 0; t < NT; ++t) {
    if (t + 1 < NT) stage(As[(t + 1) & 1], Bs[(t + 1) & 1], (t + 1) * 64);
    compute(As[t & 1], Bs[t & 1]);
    __syncthreads();
  }

  #pragma unroll
  for (int m = 0; m < 4; ++m) {
    #pragma unroll
    for (int n = 0; n < 4; ++n) {
      #pragma unroll
      for (int r = 0; r < 4; ++r) {
        const int row = m0 + wm + m * 16 + kgf * 4 + r;
        const int col = n0 + wn + n * 16 + lr;
        float v = acc[m][n][r];
        if constexpr (EPI == 0) {
          const int which = col >> 8, c = col & 255;
          const float* bp = which == 0 ? bias0 : (which == 1 ? bias1 : bias2);
          v += bp[c];
          Obf[(size_t)which * kRows * kC + (size_t)row * kC + c] = __float2bfloat16(v);
        } else if constexpr (EPI == 1) {
          v += bias0[col];
          const float gl = 0.5f * v * (1.f + erff(v * 0.70710678118654752f));
          Obf[(size_t)row * kFF + col] = __float2bfloat16(gl);
        } else {
          v += bias0[col] + Ares[(size_t)row * kC + col];
          int b, g1, g2; row_coords(row, b, g1, g2);
          Out[(((size_t)b * kGRID + g1) * kGRID + g2) * kC + col] = v;
        }
      }
    }
  }
}

// ---------------- MFMA attention (unchanged)
constexpr int kKsPad = 40;   // rows 16B-aligned (80B), 2-way banks
constexpr int kVtPad = 200;  // rows 16B-aligned (400B), 2-way banks
constexpr int kPlPad = 200;
__global__ __launch_bounds__(256) void k_attn(
    const bf16_t* __restrict__ Q, const bf16_t* __restrict__ K,
    const bf16_t* __restrict__ V, const float* __restrict__ pos,
    bf16_t* __restrict__ SA) {
  __shared__ short Ks[kP * kKsPad];        // K rows [192][40]
  __shared__ short Vt[kDh * kVtPad];       // V^T    [32][200]
  __shared__ short Pl[4 * 16 * kPlPad];    // per-wave P m-tile [16][200]
  const int bw = blockIdx.x >> 3, h = blockIdx.x & 7;
  const int rowbase = bw * kP, colbase = h * kDh;
  const int tid = threadIdx.x, wave = tid >> 6, lane = tid & 63;
  const int lr = lane & 15, kg = lane >> 4;
  const int wq0 = wave * 48;
  const float* pb = pos + (size_t)h * kP * kP;

  #pragma unroll
  for (int i = 0; i < 3; ++i) {
    const int c = tid + i * 256;           // 768 chunks of 8 elems
    const int row = c >> 2, dch = (c & 3) * 8;
    const size_t gbase = (size_t)(rowbase + row) * kC + colbase + dch;
    bf16x8 kv = *reinterpret_cast<const bf16x8*>(K + gbase);
    *reinterpret_cast<bf16x8*>(&Ks[row * kKsPad + dch]) = kv;
    bf16x8 vv = *reinterpret_cast<const bf16x8*>(V + gbase);
    #pragma unroll
    for (int e = 0; e < 8; ++e) Vt[(dch + e) * kVtPad + row] = vv[e];
  }
  __syncthreads();

  for (int m = 0; m < 3; ++m) {
    const int rbase = wq0 + m * 16;
    bf16x8 aq = *reinterpret_cast<const bf16x8*>(
        Q + (size_t)(rowbase + rbase + lr) * kC + colbase + kg * 8);
    f32x4 s[12];
    #pragma unroll
    for (int n = 0; n < 12; ++n) {
      bf16x8 bk = *reinterpret_cast<const bf16x8*>(&Ks[(n * 16 + lr) * kKsPad + kg * 8]);
      s[n] = __builtin_amdgcn_mfma_f32_16x16x32_bf16(aq, bk, (f32x4){0.f, 0.f, 0.f, 0.f}, 0, 0, 0);
    }
    float mx[4] = {-1e30f, -1e30f, -1e30f, -1e30f};
    #pragma unroll
    for (int n = 0; n < 12; ++n) {
      #pragma unroll
      for (int r = 0; r < 4; ++r) {
        const float lg = fmaf(s[n][r], kScale,
                              pb[(size_t)(rbase + kg * 4 + r) * kP + n * 16 + lr]);
        s[n][r] = lg;
        mx[r] = fmaxf(mx[r], lg);
      }
    }
    #pragma unroll
    for (int r = 0; r < 4; ++r)
      #pragma unroll
      for (int off = 8; off; off >>= 1) mx[r] = fmaxf(mx[r], __shfl_xor(mx[r], off));
    float sm[4] = {0.f, 0.f, 0.f, 0.f};
    #pragma unroll
    for (int n = 0; n < 12; ++n)
      #pragma unroll
      for (int r = 0; r < 4; ++r) {
        const float e = __expf(s[n][r] - mx[r]);
        s[n][r] = e;
        sm[r] += e;
      }
    #pragma unroll
    for (int r = 0; r < 4; ++r) {
      #pragma unroll
      for (int off = 8; off; off >>= 1) sm[r] += __shfl_xor(sm[r], off);
      sm[r] = 1.f / sm[r];
    }
    #pragma unroll
    for (int n = 0; n < 12; ++n)
      #pragma unroll
      for (int r = 0; r < 4; ++r)
        Pl[(wave * 16 + kg * 4 + r) * kPlPad + n * 16 + lr] = f2bf(s[n][r] * sm[r]);
    f32x4 o0 = {0.f, 0.f, 0.f, 0.f}, o1 = {0.f, 0.f, 0.f, 0.f};
    #pragma unroll
    for (int kk = 0; kk < 6; ++kk) {
      bf16x8 ap = *reinterpret_cast<const bf16x8*>(&Pl[(wave * 16 + lr) * kPlPad + kk * 32 + kg * 8]);
      bf16x8 b0 = *reinterpret_cast<const bf16x8*>(&Vt[lr * kVtPad + kk * 32 + kg * 8]);
      bf16x8 b1 = *reinterpret_cast<const bf16x8*>(&Vt[(16 + lr) * kVtPad + kk * 32 + kg * 8]);
      o0 = __builtin_amdgcn_mfma_f32_16x16x32_bf16(ap, b0, o0, 0, 0, 0);
      o1 = __builtin_amdgcn_mfma_f32_16x16x32_bf16(ap, b1, o1, 0, 0, 0);
    }
    bf16_t* sp = SA + (size_t)(rowbase + rbase + kg * 4) * kC + colbase;
    #pragma unroll
    for (int r = 0; r < 4; ++r) {
      sp[(size_t)r * kC + lr]      = __float2bfloat16(o0[r]);
      sp[(size_t)r * kC + 16 + lr] = __float2bfloat16(o1[r]);
    }
  }
}

extern "C" void kernel_launch(void* const* d_in, const int* in_sizes, int n_in,
                              void* d_out, int out_size, void* d_ws, size_t ws_size,
                              hipStream_t stream) {
  const float* emb  = (const float*)d_in[0];
  const float* ln1g = (const float*)d_in[1];
  const float* ln1b = (const float*)d_in[2];
  const float* wq   = (const float*)d_in[3];
  const float* bq   = (const float*)d_in[4];
  const float* wk   = (const float*)d_in[5];
  const float* bk   = (const float*)d_in[6];
  const float* wv   = (const float*)d_in[7];
  const float* bv   = (const float*)d_in[8];
  const float* pos  = (const float*)d_in[9];
  const float* ln2g = (const float*)d_in[10];
  const float* ln2b = (const float*)d_in[11];
  const float* w1   = (const float*)d_in[12];
  const float* b1   = (const float*)d_in[13];
  const float* w2   = (const float*)d_in[14];
  const float* b2   = (const float*)d_in[15];

  char* ws = (char*)d_ws;
  const size_t nYb = (size_t)kRows * kC * 2;               // 18,874,368 B
  bf16_t* Y    = (bf16_t*)(ws);                            // [0, 18.9M)
  bf16_t* Qb   = (bf16_t*)(ws + nYb);                      // Q,K,V consecutive
  bf16_t* SAb  = (bf16_t*)(ws + nYb * 4);                  // [75.5M, 94.4M)
  float*  Abuf = (float*) (ws + nYb * 5);                  // [94.4M, 132.1M)
  bf16_t* H    = (bf16_t*)(ws + nYb * 5 + (size_t)kRows * kC * 4);  // [132.1M, 151M)
  bf16_t* G    = (bf16_t*)(ws);                            // alias dead Y/Q/K/V
  bf16_t* W    = (bf16_t*)(ws + nYb * 5 + (size_t)kRows * kC * 4 + nYb);
  bf16_t* WqkvT = W;
  bf16_t* W1T   = W + 768 * 256;
  bf16_t* W2T   = W1T + 1024 * 256;

  k_wconv<<<2816, 256, 0, stream>>>(wq, wk, wv, w1, w2, W);
  k_ln1<<<kRows / 8, 256, 0, stream>>>(emb, ln1g, ln1b, Y);
  k_gemm3<256, 0, 6><<<(kRows / 128) * 6, 256, 0, stream>>>(
      Y, WqkvT, bq, bk, bv, Qb, nullptr, nullptr);
  k_attn<<<kB * kNW * kNH, 256, 0, stream>>>(
      Qb, Qb + (size_t)kRows * kC, Qb + 2 * (size_t)kRows * kC, pos, SAb);
  k_ln2<<<kRows / 8, 256, 0, stream>>>(emb, SAb, ln2g, ln2b, Abuf, H);
  k_gemm3<256, 1, 8><<<(kRows / 128) * 8, 256, 0, stream>>>(
      H, W1T, b1, nullptr, nullptr, G, nullptr, nullptr);
  k_gemm3<1024, 2, 2><<<(kRows / 128) * 2, 256, 0, stream>>>(
      G, W2T, b2, nullptr, nullptr, nullptr, Abuf, (float*)d_out);
}